// Round 1
// 998.373 us; speedup vs baseline: 1.3665x; 1.3665x over previous
//
#include <hip/hip_runtime.h>
#include <stdint.h>

#define K 32
#define BLOCK 256
#define EPB (BLOCK * 8)      // 2048 elements per sweep iteration
#define QCAP 3072            // survivor queue capacity (24 KB LDS)
#define NWAVE (BLOCK / 64)
#define THRESH_RANK 8        // threshold = 8th-largest of 2048 samples

// Pack a key into a uint64 whose unsigned ordering == (key asc, then index desc).
// Larger packed = larger key; among equal keys, smaller index wins (matches lax.top_k).
__device__ __forceinline__ unsigned long long pack_key(float r, float p, unsigned idx) {
    float key = logf(r) / p;
    unsigned kb = __float_as_uint(key);
    unsigned ord = (kb & 0x80000000u) ? ~kb : (kb | 0x80000000u);
    return ((unsigned long long)ord << 32) | (unsigned long long)(~idx);
}

__device__ __forceinline__ void heap_siftdown(volatile unsigned long long* H, int size,
                                              unsigned long long x) {
    int i = 0;
    for (;;) {
        int l = 2 * i + 1;
        if (l >= size) break;
        int r = l + 1;
        int m = l;
        unsigned long long vm = H[l];
        if (r < size) {
            unsigned long long vr = H[r];
            if (vr < vm) { m = r; vm = vr; }
        }
        if (vm >= x) break;
        H[i] = vm;
        i = m;
    }
    H[i] = x;
}

// Push a candidate into the block survivor queue if it beats the threshold.
#define PUSH(rr, pp, ii) do {                                              \
    unsigned long long _k = pack_key((rr), (pp), (unsigned)(ii));          \
    if (_k > thr) {                                                        \
        int _s = atomicAdd(&s_qcount, 1);                                  \
        if (_s < QCAP) s_queue[_s] = _k; else s_overflow = 1;              \
    } } while (0)

__global__ __launch_bounds__(BLOCK) void topk_race_kernel(
    const float* __restrict__ probs,
    const float* __restrict__ rnd,
    int* __restrict__ out,
    int V)
{
    __shared__ unsigned long long s_queue[QCAP];
    __shared__ unsigned long long s_wred[NWAVE];
    __shared__ int s_qcount;
    __shared__ int s_overflow;
    // fallback-path state (statistically never used; kept for exactness)
    __shared__ unsigned long long s_heap[K];
    __shared__ unsigned long long s_thr;

    const int row = blockIdx.x;
    const int tid = threadIdx.x;
    const int lane = tid & 63;
    const int wid = tid >> 6;
    const float* __restrict__ prow = probs + (size_t)row * V;
    const float* __restrict__ rrow = rnd   + (size_t)row * V;

    if (tid == 0) { s_qcount = 0; s_overflow = 0; }

    // ---------- Phase 0: sample 2048 elements, threshold = 8th-largest ----------
    unsigned long long smp[THRESH_RANK];
    {
        const int sstep = V / THRESH_RANK;   // 8 coalesced regions of BLOCK elems
        #pragma unroll
        for (int j = 0; j < THRESH_RANK; ++j) {
            int idx = j * sstep + tid;
            if (idx >= V) idx = V - 1;
            smp[j] = pack_key(rrow[idx], prow[idx], (unsigned)idx);
        }
    }
    __syncthreads();   // also publishes s_qcount/s_overflow init

    unsigned long long thr = 0;
    for (int it = 0; it < THRESH_RANK; ++it) {
        unsigned long long m = 0;
        #pragma unroll
        for (int j = 0; j < THRESH_RANK; ++j) m = (smp[j] > m) ? smp[j] : m;
        #pragma unroll
        for (int off = 1; off < 64; off <<= 1) {
            unsigned long long o = __shfl_xor(m, off, 64);
            if (o > m) m = o;
        }
        if (lane == 0) s_wred[wid] = m;
        __syncthreads();
        unsigned long long bm = s_wred[0];
        #pragma unroll
        for (int w = 1; w < NWAVE; ++w) bm = (s_wred[w] > bm) ? s_wred[w] : bm;
        // exactly one (thread, slot) holds bm (indices make keys unique) — clear it
        #pragma unroll
        for (int j = 0; j < THRESH_RANK; ++j) if (smp[j] == bm) smp[j] = 0;
        thr = bm;
        __syncthreads();
    }

    // ---------- Phase 1: barrier-free streaming filter (memory-bound part) ----------
    const int nepoch = (V + EPB - 1) / EPB;

    float4 pA, rA, pB, rB;
    {
        const int b0 = tid * 4;
        const int b1 = b0 + BLOCK * 4;
        if (b0 + 3 < V) { pA = *(const float4*)(prow + b0); rA = *(const float4*)(rrow + b0); }
        if (b1 + 3 < V) { pB = *(const float4*)(prow + b1); rB = *(const float4*)(rrow + b1); }
    }
    bool vA = (tid * 4 + 3 < V);
    bool vB = (tid * 4 + BLOCK * 4 + 3 < V);

    for (int e = 0; e < nepoch; ++e) {
        const int base = e * EPB + tid * 4;

        // prefetch next epoch into registers before touching this one
        float4 npA, nrA, npB, nrB;
        bool nvA = false, nvB = false;
        {
            const int nb0 = base + EPB;
            const int nb1 = nb0 + BLOCK * 4;
            nvA = (nb0 + 3 < V);
            nvB = (nb1 + 3 < V);
            if (nvA) { npA = *(const float4*)(prow + nb0); nrA = *(const float4*)(rrow + nb0); }
            if (nvB) { npB = *(const float4*)(prow + nb1); nrB = *(const float4*)(rrow + nb1); }
        }

        if (vA) {
            PUSH(rA.x, pA.x, base + 0);
            PUSH(rA.y, pA.y, base + 1);
            PUSH(rA.z, pA.z, base + 2);
            PUSH(rA.w, pA.w, base + 3);
        }
        if (vB) {
            const int b = base + BLOCK * 4;
            PUSH(rB.x, pB.x, b + 0);
            PUSH(rB.y, pB.y, b + 1);
            PUSH(rB.z, pB.z, b + 2);
            PUSH(rB.w, pB.w, b + 3);
        }

        pA = npA; rA = nrA; pB = npB; rB = nrB;
        vA = nvA; vB = nvB;
    }

    __syncthreads();
    const int n = s_qcount;
    const bool ok = (n >= K) && (s_overflow == 0);
    int* __restrict__ orow = out + (size_t)row * K;

    if (ok) {
        // ---------- Phase 2: 32 parallel max-extractions over ~500 survivors ----------
        for (int k = 0; k < K; ++k) {
            unsigned long long m = 0;
            for (int q = tid; q < n; q += BLOCK) {
                unsigned long long v = s_queue[q];
                if (v > m) m = v;
            }
            #pragma unroll
            for (int off = 1; off < 64; off <<= 1) {
                unsigned long long o = __shfl_xor(m, off, 64);
                if (o > m) m = o;
            }
            if (lane == 0) s_wred[wid] = m;
            __syncthreads();
            unsigned long long bm = s_wred[0];
            #pragma unroll
            for (int w = 1; w < NWAVE; ++w) bm = (s_wred[w] > bm) ? s_wred[w] : bm;
            // owner clears its (unique) winning slot; disjoint strided partitions => no race
            for (int q = tid; q < n; q += BLOCK) {
                if (s_queue[q] == bm) s_queue[q] = 0;
            }
            if (tid == 0) orow[k] = (int)(~(unsigned)(bm & 0xFFFFFFFFull));
            __syncthreads();
        }
        return;
    }

    // ---------- Fallback (provably-correct original epoch+heap path; ~never taken) ----------
    if (tid < K) s_heap[tid] = 0ull;
    if (tid == 0) { s_qcount = 0; s_thr = 0ull; }
    __syncthreads();

    for (int e = 0; e < nepoch; ++e) {
        const unsigned long long fthr = s_thr;
        const int eb = e * EPB;
        const int fb0 = eb + tid * 4;
        const int fb1 = eb + BLOCK * 4 + tid * 4;

        unsigned long long pk[8];
        int npk = 0;

        if (fb0 + 3 < V) {
            const float4 p = *(const float4*)(prow + fb0);
            const float4 r = *(const float4*)(rrow + fb0);
            pk[npk++] = pack_key(r.x, p.x, (unsigned)(fb0 + 0));
            pk[npk++] = pack_key(r.y, p.y, (unsigned)(fb0 + 1));
            pk[npk++] = pack_key(r.z, p.z, (unsigned)(fb0 + 2));
            pk[npk++] = pack_key(r.w, p.w, (unsigned)(fb0 + 3));
        }
        if (fb1 + 3 < V) {
            const float4 p = *(const float4*)(prow + fb1);
            const float4 r = *(const float4*)(rrow + fb1);
            pk[npk++] = pack_key(r.x, p.x, (unsigned)(fb1 + 0));
            pk[npk++] = pack_key(r.y, p.y, (unsigned)(fb1 + 1));
            pk[npk++] = pack_key(r.z, p.z, (unsigned)(fb1 + 2));
            pk[npk++] = pack_key(r.w, p.w, (unsigned)(fb1 + 3));
        }

        #pragma unroll
        for (int j = 0; j < 8; ++j) {
            if (j < npk && pk[j] > fthr) {
                int slot = atomicAdd(&s_qcount, 1);
                s_queue[slot] = pk[j];
            }
        }

        __syncthreads();
        if (tid == 0) {
            const int nq = s_qcount;
            unsigned long long root = s_heap[0];
            for (int q = 0; q < nq; ++q) {
                unsigned long long x = s_queue[q];
                if (x > root) {
                    heap_siftdown(s_heap, K, x);
                    root = s_heap[0];
                }
            }
            s_qcount = 0;
            s_thr = root;
        }
        __syncthreads();
    }

    if (tid == 0) {
        int size = K;
        for (int k = 0; k < K; ++k) {
            unsigned long long top = s_heap[0];
            orow[K - 1 - k] = (int)(~(unsigned)(top & 0xFFFFFFFFull));
            --size;
            unsigned long long x = s_heap[size];
            heap_siftdown(s_heap, size, x);
        }
    }
}

extern "C" void kernel_launch(void* const* d_in, const int* in_sizes, int n_in,
                              void* d_out, int out_size, void* d_ws, size_t ws_size,
                              hipStream_t stream) {
    const float* probs = (const float*)d_in[0];
    const float* rnd   = (const float*)d_in[1];
    int* out = (int*)d_out;

    const int B = out_size / (K * (int)sizeof(int)) > 0 ? out_size / (K * (int)sizeof(int)) : out_size / K;
    // out_size semantics follow the prior harness-verified kernel: out_size / K rows
    const int B_rows = out_size / K;
    const int V = in_sizes[0] / B_rows;

    topk_race_kernel<<<B_rows, BLOCK, 0, stream>>>(probs, rnd, out, V);
}